// Round 8
// baseline (384.594 us; speedup 1.0000x reference)
//
#include <hip/hip_runtime.h>
#include <hip/hip_bf16.h>

#define B_ 64
#define T_ 2048
#define D_ 512     // K dim of GEMM (KD=QD)
#define A_ 512     // attention dim (N of GEMM)
#define BM 64      // t-rows per block (A panel persistent in LDS)
#define BK 32      // K step
#define NSTEP (D_/BK)   // 16
#define NCT 4           // sequential 128-col passes
#define CH 4112         // padded LDS chunk stride in bytes (4096 + 16)

typedef float f32x4_t __attribute__((ext_vector_type(4)));
typedef short bf16x8_t __attribute__((ext_vector_type(8)));

// ---------------- prep: q = query @ Wq + bq (fp32, exact) ----------------
__global__ void __launch_bounds__(256) qproj_kernel(
    const float* __restrict__ query, const float* __restrict__ Wq,
    const float* __restrict__ bq, float* __restrict__ qbuf) {
  __shared__ float qs[D_];
  const int b = blockIdx.x, tid = threadIdx.x;
  qs[tid] = query[b*D_ + tid];
  qs[tid+256] = query[b*D_ + tid + 256];
  __syncthreads();
  float a0 = bq[tid], a1 = bq[tid+256];
  for (int d = 0; d < D_; ++d) {
    const float qv = qs[d];
    a0 += qv * Wq[d*A_ + tid];
    a1 += qv * Wq[d*A_ + tid + 256];
  }
  qbuf[b*A_ + tid] = a0;
  qbuf[b*A_ + tid+256] = a1;
}

// ---- prep: Wk [D][A] fp32 -> bf16 slab (PLAIN layout) ----
// slab row (kb, a): 64 B = 4 slots of 8 bf16, slot c = k-octet kb*32 + c*8.
// B-fragment (col a, k-octet lq) = slab + ((kb*512 + a)*64 + lq*16) bytes.
__global__ void __launch_bounds__(256) wkprep_kernel(
    const float* __restrict__ Wk, unsigned int* __restrict__ slab) {
  __shared__ float tile[32][65];
  const int kb = blockIdx.x >> 3;
  const int a0 = (blockIdx.x & 7) * 64;
  const int tid = threadIdx.x;
  for (int p = 0; p < 8; ++p) {
    const int idx = p*256 + tid;
    const int k = idx >> 6, al = idx & 63;
    tile[k][al] = Wk[(kb*32 + k)*A_ + a0 + al];
  }
  __syncthreads();
  const int al = tid >> 2, c = tid & 3;
  const int a = a0 + al;
  union { __hip_bfloat162 h[2]; uint2 u; } w0, w1;
  w0.h[0] = __float22bfloat162_rn(make_float2(tile[c*8+0][al], tile[c*8+1][al]));
  w0.h[1] = __float22bfloat162_rn(make_float2(tile[c*8+2][al], tile[c*8+3][al]));
  w1.h[0] = __float22bfloat162_rn(make_float2(tile[c*8+4][al], tile[c*8+5][al]));
  w1.h[1] = __float22bfloat162_rn(make_float2(tile[c*8+6][al], tile[c*8+7][al]));
  *(uint4*)(slab + (kb*512 + a)*16 + c*4) =
      make_uint4(w0.u.x, w0.u.y, w1.u.x, w1.u.y);
}

// ------- fused energy: A-panel persistent in LDS, barrier-free 64-step loop -------
// Block = 64 t-rows x full A (4 sequential 128-col passes). 8 waves, wave tile 16x64.
// A LDS chunk ks: [64 rows][4 slots of 16 B], slot s holds k-octet s ^ ((row>>1)&3)
// (R1-measured conflict-free ds_read_b128 pattern); chunk stride padded +16 B.
__global__ void __launch_bounds__(512, 4) energy_kernel(
    const float* __restrict__ keys, const float* __restrict__ cover,
    const int* __restrict__ key_len, const unsigned char* __restrict__ slabB,
    const float* __restrict__ qbuf, const float* __restrict__ Wc,
    const float* __restrict__ Wo, float* __restrict__ energy) {
  __shared__ __align__(16) unsigned char Apan[NSTEP*CH];   // ~64.25 KB
  __shared__ float redbuf[8][16];

  const int d = blockIdx.x;        // 0..2047
  const int b = d >> 5;
  const int tt = d & 31;
  const int t0 = tt * BM;
  const int kl = key_len[b];
  if (t0 >= kl) return;            // fully-masked tile

  const int tid = threadIdx.x;
  const int wid = tid >> 6;        // 0..7
  const int lane = tid & 63;
  const int lq = lane >> 4, lr = lane & 15;
  const int wm = wid & 3;          // row group: rows wm*16 .. +16
  const int wn = wid >> 2;         // col half: cols wn*64 .. +64 (within ct's 128)

  // ---- prologue: stage the whole A panel fp32->bf16 into LDS (once) ----
  {
    const int g = lane;            // granule 0..63: ks = g>>2, c = g&3
    const int ks = g >> 2, c = g & 3;
    #pragma unroll
    for (int p = 0; p < 8; ++p) {
      const int row = p*8 + wid;   // wave-uniform row; lanes sweep 2 KB contiguous
      const float* src = keys + ((size_t)b*T_ + t0 + row)*D_ + g*8;
      const f32x4_t v0 = *(const f32x4_t*)(src);
      const f32x4_t v1 = *(const f32x4_t*)(src + 4);
      union { __hip_bfloat162 h[2]; uint2 u; } q0, q1;
      q0.h[0] = __float22bfloat162_rn(make_float2(v0[0], v0[1]));
      q0.h[1] = __float22bfloat162_rn(make_float2(v0[2], v0[3]));
      q1.h[0] = __float22bfloat162_rn(make_float2(v1[0], v1[1]));
      q1.h[1] = __float22bfloat162_rn(make_float2(v1[2], v1[3]));
      const int slot = c ^ ((row >> 1) & 3);
      *(uint4*)(Apan + ks*CH + row*64 + slot*16) =
          make_uint4(q0.u.x, q0.u.y, q1.u.x, q1.u.y);
    }
  }
  __syncthreads();

  // A fragment read base: one VGPR address + ks*CH immediate offsets
  const int ar = wm*16 + lr;
  const unsigned char* abase = Apan + ar*64 + ((lq ^ ((ar >> 1) & 3)) << 4);

  float cov[4];
  #pragma unroll
  for (int j = 0; j < 4; ++j)
    cov[j] = cover[(size_t)b*T_ + t0 + wm*16 + lq*4 + j];

  float ep[4] = {0.f, 0.f, 0.f, 0.f};

  #pragma unroll
  for (int ct = 0; ct < NCT; ++ct) {
    f32x4_t acc[4];
    #pragma unroll
    for (int nf = 0; nf < 4; ++nf) acc[nf] = 0.0f;

    #pragma unroll
    for (int ks = 0; ks < NSTEP; ++ks) {
      const bf16x8_t aF = *(const bf16x8_t*)(abase + ks*CH);
      #pragma unroll
      for (int nf = 0; nf < 4; ++nf) {
        const int n = ct*128 + wn*64 + nf*16 + lr;
        const bf16x8_t bF = *(const bf16x8_t*)(
            slabB + ((size_t)(ks*A_ + n))*64 + lq*16);
        acc[nf] = __builtin_amdgcn_mfma_f32_16x16x32_bf16(aF, bF, acc[nf], 0, 0, 0);
      }
    }

    // epilogue for this ct: ep[j] += sum_nf Wo[n]*tanh(acc + q[n] + cov*Wc[n])
    #pragma unroll
    for (int nf = 0; nf < 4; ++nf) {
      const int n = ct*128 + wn*64 + nf*16 + lr;
      const float qv = qbuf[b*A_ + n];
      const float wc = Wc[n];
      const float wo = Wo[n];
      #pragma unroll
      for (int j = 0; j < 4; ++j) {
        float p = acc[nf][j] + qv + cov[j] * wc;
        p = fminf(fmaxf(p, -15.f), 15.f);
        const float t2 = __expf(2.f * p);
        ep[j] += wo * ((t2 - 1.f) * __builtin_amdgcn_rcpf(t2 + 1.f));
      }
    }
  }

  // reduce over the 16 lr-lanes, then across the two wn waves per row group
  #pragma unroll
  for (int j = 0; j < 4; ++j) {
    float v = ep[j];
    v += __shfl_xor(v, 1); v += __shfl_xor(v, 2);
    v += __shfl_xor(v, 4); v += __shfl_xor(v, 8);
    ep[j] = v;
  }
  if (lr == 0) {
    #pragma unroll
    for (int j = 0; j < 4; ++j)
      redbuf[wid][lq*4 + j] = ep[j];
  }
  __syncthreads();
  if (tid < BM) {
    const int r = tid;
    energy[(size_t)b*T_ + t0 + r] =
        redbuf[r >> 4][r & 15] + redbuf[4 + (r >> 4)][r & 15];
  }
}

// ---------------- masked softmax over T ----------------
__global__ void __launch_bounds__(1024) softmax_kernel(
    const float* __restrict__ energy, const int* __restrict__ key_len,
    float* __restrict__ attn) {
  __shared__ float sredM[16];
  __shared__ float sredS[16];
  const int b = blockIdx.x, tid = threadIdx.x;
  const int kl = key_len[b];
  const float e0 = (tid < kl) ? energy[(size_t)b*T_ + tid] : -3.0e38f;
  const float e1 = (tid + 1024 < kl) ? energy[(size_t)b*T_ + tid + 1024] : -3.0e38f;
  float m = fmaxf(e0, e1);
  for (int s = 32; s; s >>= 1) m = fmaxf(m, __shfl_xor(m, s));
  if ((tid & 63) == 0) sredM[tid >> 6] = m;
  __syncthreads();
  float M = -3.0e38f;
  #pragma unroll
  for (int i = 0; i < 16; ++i) M = fmaxf(M, sredM[i]);
  const float p0 = (tid < kl) ? __expf(e0 - M) : 0.f;
  const float p1 = (tid + 1024 < kl) ? __expf(e1 - M) : 0.f;
  float s = p0 + p1;
  for (int k = 32; k; k >>= 1) s += __shfl_xor(s, k);
  if ((tid & 63) == 0) sredS[tid >> 6] = s;
  __syncthreads();
  float S = 0.f;
  #pragma unroll
  for (int i = 0; i < 16; ++i) S += sredS[i];
  const float inv = 1.f / S;
  attn[b*T_ + tid] = p0 * inv;
  attn[b*T_ + tid + 1024] = p1 * inv;
}

// ---------------- context: partial sums over t-chunks (float4), then combine ----------------
__global__ void __launch_bounds__(256) ctxpart_kernel(
    const float* __restrict__ value, const float* __restrict__ attn,
    const int* __restrict__ key_len, float* __restrict__ partial) {
  __shared__ float att_s[256];
  __shared__ float4 comb[128];
  const int b = blockIdx.y, ch = blockIdx.x;
  const int tid = threadIdx.x;
  const int c4 = tid & 127, half = tid >> 7;
  const int kl = key_len[b];
  const int tstart = ch * 256;
  const int tend = min(256, kl - tstart);
  float4 acc = make_float4(0.f, 0.f, 0.f, 0.f);
  if (tend > 0) {
    att_s[tid] = attn[b*T_ + tstart + tid];
    __syncthreads();
    const float4* vp = (const float4*)(value + ((size_t)b*T_ + tstart)*D_) + c4;
    for (int i = half; i < tend; i += 2) {
      const float w = att_s[i];
      const float4 v = vp[(size_t)i * 128];
      acc.x += w * v.x; acc.y += w * v.y; acc.z += w * v.z; acc.w += w * v.w;
    }
  }
  if (half == 1) comb[c4] = acc;
  __syncthreads();
  if (half == 0) {
    const float4 o = comb[c4];
    acc.x += o.x; acc.y += o.y; acc.z += o.z; acc.w += o.w;
    ((float4*)(partial + (size_t)(b*8 + ch)*D_))[c4] = acc;
  }
}

__global__ void __launch_bounds__(128) ctxsum_kernel(
    const float* __restrict__ partial, float* __restrict__ ctx) {
  const int b = blockIdx.x, tid = threadIdx.x;
  float4 s = make_float4(0.f, 0.f, 0.f, 0.f);
  #pragma unroll
  for (int c = 0; c < 8; ++c) {
    const float4 v = ((const float4*)(partial + (size_t)(b*8 + c)*D_))[tid];
    s.x += v.x; s.y += v.y; s.z += v.z; s.w += v.w;
  }
  ((float4*)(ctx + (size_t)b*D_))[tid] = s;
}

extern "C" void kernel_launch(void* const* d_in, const int* in_sizes, int n_in,
                              void* d_out, int out_size, void* d_ws, size_t ws_size,
                              hipStream_t stream) {
  const float* query  = (const float*)d_in[0];
  const float* keys   = (const float*)d_in[1];
  const float* value  = (const float*)d_in[2];
  const float* cover  = (const float*)d_in[3];
  const int*   key_len= (const int*)d_in[4];
  const float* Wq     = (const float*)d_in[5];
  const float* bq     = (const float*)d_in[6];
  const float* Wk     = (const float*)d_in[7];
  const float* Wc     = (const float*)d_in[8];
  const float* Wo     = (const float*)d_in[9];

  float* out = (float*)d_out;
  float* ctx_out  = out;            // [64,512]
  float* attn_out = out + B_*A_;    // [64,1,2048]

  float* ws = (float*)d_ws;
  float* qbuf    = ws;                                   // 32768 f32
  float* energy  = ws + 32768;                           // 131072 f32
  float* partial = ws + 32768 + 131072;                  // 262144 f32
  unsigned int* slab = (unsigned int*)(ws + 32768 + 131072 + 262144);  // 512 KB

  qproj_kernel<<<B_, 256, 0, stream>>>(query, Wq, bq, qbuf);
  wkprep_kernel<<<128, 256, 0, stream>>>(Wk, slab);
  energy_kernel<<<B_*(T_/BM), 512, 0, stream>>>(
      keys, cover, key_len, (const unsigned char*)slab, qbuf, Wc, Wo, energy);
  softmax_kernel<<<B_, 1024, 0, stream>>>(energy, key_len, attn_out);
  ctxpart_kernel<<<dim3(8, B_), 256, 0, stream>>>(value, attn_out, key_len, partial);
  ctxsum_kernel<<<B_, 128, 0, stream>>>(partial, ctx_out);
}

// Round 9
// 270.716 us; speedup vs baseline: 1.4207x; 1.4207x over previous
//
#include <hip/hip_runtime.h>
#include <hip/hip_bf16.h>

#define B_ 64
#define T_ 2048
#define D_ 512     // K dim of GEMM
#define A_ 512     // attention dim (N of GEMM)
#define BMT 256    // t-rows per block
#define BNT 256    // a-cols per block (N split in 2)
#define NIT 4      // K iterations, 2 tiles of BK=64 each

typedef float f32x4_t __attribute__((ext_vector_type(4)));
typedef short bf16x8_t __attribute__((ext_vector_type(8)));

#define GLL16(g, l) __builtin_amdgcn_global_load_lds( \
    (const __attribute__((address_space(1))) void*)(g), \
    (__attribute__((address_space(3))) void*)(l), 16, 0, 0)

#define SBAR __builtin_amdgcn_s_barrier()
#define LGKM0 do { asm volatile("s_waitcnt lgkmcnt(0)" ::: "memory"); \
                   __builtin_amdgcn_sched_barrier(0); } while (0)
#define VMW(N) asm volatile("s_waitcnt vmcnt(" #N ")" ::: "memory")

// ---------------- prep: q = query @ Wq + bq (fp32, exact) ----------------
__global__ void __launch_bounds__(256) qproj_kernel(
    const float* __restrict__ query, const float* __restrict__ Wq,
    const float* __restrict__ bq, float* __restrict__ qbuf) {
  __shared__ float qs[D_];
  const int b = blockIdx.x, tid = threadIdx.x;
  qs[tid] = query[b*D_ + tid];
  qs[tid+256] = query[b*D_ + tid + 256];
  __syncthreads();
  float a0 = bq[tid], a1 = bq[tid+256];
  for (int d = 0; d < D_; ++d) {
    const float qv = qs[d];
    a0 += qv * Wq[d*A_ + tid];
    a1 += qv * Wq[d*A_ + tid + 256];
  }
  qbuf[b*A_ + tid] = a0;
  qbuf[b*A_ + tid+256] = a1;
}

// ---- prep: Wk [D][A] fp32 -> slab [kt=8][ct=2][n=256][slot=8 x 16B] ----
// slot s of col n holds k-octet o = s ^ (n&7) (st-swizzle baked in; GLL copies
// linearly, ds_read applies the same XOR -> conflict-free b128).
__global__ void __launch_bounds__(256) wkprep_kernel(
    const float* __restrict__ Wk, unsigned int* __restrict__ slab) {
  __shared__ float tile[64][65];
  const int kt = blockIdx.x >> 3;
  const int a0 = (blockIdx.x & 7) * 64;
  const int tid = threadIdx.x;
  #pragma unroll
  for (int p = 0; p < 16; ++p) {
    const int idx = p*256 + tid;
    const int k = idx >> 6, al = idx & 63;
    tile[k][al] = Wk[(kt*64 + k)*A_ + a0 + al];
  }
  __syncthreads();
  #pragma unroll
  for (int w = 0; w < 2; ++w) {
    const int idx = w*256 + tid;      // 0..511
    const int al = idx >> 3, c = idx & 7;
    const int a = a0 + al;
    const int n = a & 255;
    const int ctb = a >> 8;
    const int s = c ^ (n & 7);
    union { __hip_bfloat162 h[2]; uint2 u; } x, y;
    x.h[0] = __float22bfloat162_rn(make_float2(tile[c*8+0][al], tile[c*8+1][al]));
    x.h[1] = __float22bfloat162_rn(make_float2(tile[c*8+2][al], tile[c*8+3][al]));
    y.h[0] = __float22bfloat162_rn(make_float2(tile[c*8+4][al], tile[c*8+5][al]));
    y.h[1] = __float22bfloat162_rn(make_float2(tile[c*8+6][al], tile[c*8+7][al]));
    *(uint4*)(slab + ((kt*2 + ctb)*256 + n)*32 + s*4) =
        make_uint4(x.u.x, x.u.y, y.u.x, y.u.y);
  }
}

// ------- fused energy: 256x256 tile, 8-phase interleave, counted vmcnt -------
__global__ void __launch_bounds__(512, 2) energy_kernel(
    const float* __restrict__ keys, const float* __restrict__ cover,
    const int* __restrict__ key_len, const unsigned char* __restrict__ slabB,
    const float* __restrict__ qbuf, const float* __restrict__ Wc,
    const float* __restrict__ Wo, float* __restrict__ epart) {
  // LDS layout: A0 @0, A1 @32768, B0 @65536, B1 @98304 (each 32 KB), red @131072
  __shared__ __align__(16) unsigned char lds[135168];

  const int d = blockIdx.x;                 // 0..1023, XCD swizzle pairs ct on one XCD
  const int logical = (d & 7) * 128 + (d >> 3);
  const int ct = logical & 1;
  const int tt = (logical >> 1) & 7;
  const int b  = logical >> 4;
  const int t0 = tt * BMT;
  const int kl = key_len[b];
  if (t0 >= kl) return;

  const int tid = threadIdx.x;
  const int wid = tid >> 6, lane = tid & 63;
  const int lq = lane >> 4, lr = lane & 15;
  const int wm = wid >> 2, wn = wid & 3;    // wave tile: 128 rows x 64 cols
  const int sx = lr & 7;

  // ds_read fragment bases (row/col stride 128 B, slot = octet ^ (row&7))
  const unsigned char* aK0 = lds + (wm*128 + lr)*128 + ((lq ^ sx) << 4);
  const unsigned char* aK1 = lds + (wm*128 + lr)*128 + (((4 + lq) ^ sx) << 4);
  const unsigned char* bK0 = lds + 65536 + (wn*64 + lr)*128 + ((lq ^ sx) << 4);
  const unsigned char* bK1 = lds + 65536 + (wn*64 + lr)*128 + (((4 + lq) ^ sx) << 4);

  // A staging role: thread covers row sr_, octets o0..o0+3 (32 floats / tile)
  const int sr_ = tid >> 1, sh_ = tid & 1;
  const float* akey = keys + ((size_t)b*T_ + t0 + sr_)*(size_t)D_ + sh_*32;
  unsigned char* const awr = lds + sr_*128;
  const int o0 = sh_*4, sxw = sr_ & 7;
  const int wof0 = ((o0+0) ^ sxw) << 4;
  const int wof1 = ((o0+1) ^ sxw) << 4;
  const int wof2 = ((o0+2) ^ sxw) << 4;
  const int wof3 = ((o0+3) ^ sxw) << 4;

  // B staging role: linear GLL copy of pre-swizzled slab tile
  const unsigned char* bsl = slabB + (size_t)ct*32768 + tid*16;
  unsigned char* const bwr = lds + 65536 + tid*16;

  f32x4_t acc[8][4];
  #pragma unroll
  for (int i = 0; i < 8; ++i)
    #pragma unroll
    for (int j = 0; j < 4; ++j) acc[i][j] = 0.0f;

  bf16x8_t aF[4], bF[4];
  f32x4_t pA0[4], pA1[4], qA0[4], qA1[4];

#define AGLOADH(kt, ARR, HF) { const float* p_ = akey + (kt)*64 + (HF)*16; \
    ARR[0] = *(const f32x4_t*)(p_);      ARR[1] = *(const f32x4_t*)(p_ + 4); \
    ARR[2] = *(const f32x4_t*)(p_ + 8);  ARR[3] = *(const f32x4_t*)(p_ + 12); }

#define PACK16(dst, va, vb) { union { __hip_bfloat162 h[2]; uint2 u; } x_, y_; \
    x_.h[0] = __float22bfloat162_rn(make_float2(va[0], va[1])); \
    x_.h[1] = __float22bfloat162_rn(make_float2(va[2], va[3])); \
    y_.h[0] = __float22bfloat162_rn(make_float2(vb[0], vb[1])); \
    y_.h[1] = __float22bfloat162_rn(make_float2(vb[2], vb[3])); \
    *(uint4*)(dst) = make_uint4(x_.u.x, x_.u.y, y_.u.x, y_.u.y); }

#define APACKH(buf, ARR, W0, W1) { \
    PACK16(awr + (buf)*32768 + (W0), ARR[0], ARR[1]); \
    PACK16(awr + (buf)*32768 + (W1), ARR[2], ARR[3]); }

#define BGLL4(kt, buf) { const unsigned char* g_ = bsl + (size_t)(kt)*65536; \
    unsigned char* l_ = bwr + (buf)*32768; \
    GLL16(g_, l_); GLL16(g_ + 8192, l_ + 8192); \
    GLL16(g_ + 16384, l_ + 16384); GLL16(g_ + 24576, l_ + 24576); }

#define DSRA(buf, h, kk) { const unsigned char* p_ = ((kk) ? aK1 : aK0) + (buf)*32768 + (h)*8192; \
    aF[0] = *(const bf16x8_t*)(p_);        aF[1] = *(const bf16x8_t*)(p_ + 2048); \
    aF[2] = *(const bf16x8_t*)(p_ + 4096); aF[3] = *(const bf16x8_t*)(p_ + 6144); }

#define DSRB(buf, kk) { const unsigned char* p_ = ((kk) ? bK1 : bK0) + (buf)*32768; \
    bF[0] = *(const bf16x8_t*)(p_);        bF[1] = *(const bf16x8_t*)(p_ + 2048); \
    bF[2] = *(const bf16x8_t*)(p_ + 4096); bF[3] = *(const bf16x8_t*)(p_ + 6144); }

#define MFMA16(h) { _Pragma("unroll") for (int mf_ = 0; mf_ < 4; ++mf_) { \
    _Pragma("unroll") for (int nf_ = 0; nf_ < 4; ++nf_) \
      acc[(h)*4 + mf_][nf_] = __builtin_amdgcn_mfma_f32_16x16x32_bf16( \
          aF[mf_], bF[nf_], acc[(h)*4 + mf_][nf_], 0, 0, 0); } }

#define PH_TAIL(h) SBAR; LGKM0; __builtin_amdgcn_s_setprio(1); MFMA16(h); \
    __builtin_amdgcn_s_setprio(0); SBAR

  // ---- prologue: stage tiles 0 (bufs 0) and 1 (bufs 1) ----
  AGLOADH(0, pA0, 0); AGLOADH(0, pA1, 1);
  BGLL4(0, 0); BGLL4(1, 1);
  VMW(8);                                   // A(0) done, GLLs stay in flight
  APACKH(0, pA0, wof0, wof1); APACKH(0, pA1, wof2, wof3);
  AGLOADH(1, qA0, 0); AGLOADH(1, qA1, 1);
  VMW(0);                                   // one-time full drain
  APACKH(1, qA0, wof0, wof1); APACKH(1, qA1, wof2, wof3);
  LGKM0;
  SBAR;

  // ---- main loop: 4 iterations x 8 phases (tiles c0=2it -> buf0, c1 -> buf1) ----
  #pragma unroll
  for (int it = 0; it < NIT; ++it) {
    const int c1 = 2*it + 1, p0 = 2*it + 2, p1 = 2*it + 3;
    // ph1: c0 (h0,kk0) + B; stage B(c1)->Bbuf1
    DSRA(0, 0, 0); DSRB(0, 0);
    if (it >= 1) { BGLL4(c1, 1); }
    PH_TAIL(0);
    // ph2: c0 (h1,kk0); issue A-gloads(p0)
    DSRA(0, 1, 0);
    if (it <= 2) { AGLOADH(p0, pA0, 0); AGLOADH(p0, pA1, 1); }
    PH_TAIL(1);
    // ph3: c0 (h0,kk1) + B; pack A(c1) first half -> Abuf1
    DSRA(0, 0, 1); DSRB(0, 1);
    if (it == 1 || it == 2) { VMW(16); } else if (it == 3) { VMW(8); }
    if (it >= 1) { APACKH(1, qA0, wof0, wof1); }
    PH_TAIL(0);
    // ph4: c0 (h1,kk1); pack A(c1) second half; B(c1) publication wait
    DSRA(0, 1, 1);
    if (it == 1 || it == 2) { VMW(12); } else if (it == 3) { VMW(4); }
    if (it >= 1) { APACKH(1, qA1, wof2, wof3); }
    if (it == 1 || it == 2) { VMW(8); } else if (it == 3) { VMW(0); }
    PH_TAIL(1);
    // ph5: c1 (h0,kk0) + B; stage B(p0)->Bbuf0
    DSRA(1, 0, 0); DSRB(1, 0);
    if (it <= 2) { BGLL4(p0, 0); }
    PH_TAIL(0);
    // ph6: c1 (h1,kk0); pack A(p0) first half -> Abuf0
    DSRA(1, 1, 0);
    if (it <= 2) { VMW(8); APACKH(0, pA0, wof0, wof1); }
    PH_TAIL(1);
    // ph7: c1 (h0,kk1) + B; pack A(p0) second half
    DSRA(1, 0, 1); DSRB(1, 1);
    if (it <= 2) { VMW(4); APACKH(0, pA1, wof2, wof3); }
    PH_TAIL(0);
    // ph8: c1 (h1,kk1); issue A-gloads(p1); B(p0) publication wait
    DSRA(1, 1, 1);
    if (it <= 2) { AGLOADH(p1, qA0, 0); AGLOADH(p1, qA1, 1); VMW(8); }
    PH_TAIL(1);
  }

  // ---- epilogue: ep[t] = sum_n Wo[n] * tanh(acc + q[n] + cover[t]*Wc[n]) ----
  float* red = (float*)(lds + 131072);
  const float* qn  = qbuf + b*A_ + ct*BNT + wn*64 + lr;
  const float* wcn = Wc + ct*BNT + wn*64 + lr;
  const float* won = Wo + ct*BNT + wn*64 + lr;
  const float* covp = cover + (size_t)b*T_ + t0 + wm*128 + lq*4;
  float cov[8][4];
  #pragma unroll
  for (int mf = 0; mf < 8; ++mf)
    #pragma unroll
    for (int j = 0; j < 4; ++j) cov[mf][j] = covp[mf*16 + j];

  float ep[8][4];
  #pragma unroll
  for (int mf = 0; mf < 8; ++mf)
    #pragma unroll
    for (int j = 0; j < 4; ++j) ep[mf][j] = 0.f;

  #pragma unroll
  for (int nf = 0; nf < 4; ++nf) {
    const float qv = qn[nf*16];
    const float wc = wcn[nf*16];
    const float wo = won[nf*16];
    #pragma unroll
    for (int mf = 0; mf < 8; ++mf)
      #pragma unroll
      for (int j = 0; j < 4; ++j) {
        float p = acc[mf][nf][j] + qv + cov[mf][j] * wc;
        p = fminf(fmaxf(p, -15.f), 15.f);
        const float t2 = __expf(2.f * p);
        ep[mf][j] += wo * ((t2 - 1.f) * __builtin_amdgcn_rcpf(t2 + 1.f));
      }
  }
  #pragma unroll
  for (int mf = 0; mf < 8; ++mf)
    #pragma unroll
    for (int j = 0; j < 4; ++j) {
      float v = ep[mf][j];
      v += __shfl_xor(v, 1); v += __shfl_xor(v, 2);
      v += __shfl_xor(v, 4); v += __shfl_xor(v, 8);
      ep[mf][j] = v;
    }
  if (lr == 0) {
    #pragma unroll
    for (int mf = 0; mf < 8; ++mf)
      #pragma unroll
      for (int j = 0; j < 4; ++j)
        red[wid*128 + mf*16 + lq*4 + j] = ep[mf][j];
  }
  __syncthreads();
  if (tid < BMT) {
    const int r = tid, wmr = r >> 7, ro = r & 127;
    epart[((size_t)ct*B_ + b)*T_ + t0 + r] =
        red[(wmr*4+0)*128 + ro] + red[(wmr*4+1)*128 + ro] +
        red[(wmr*4+2)*128 + ro] + red[(wmr*4+3)*128 + ro];
  }
}

// ---------------- masked softmax over T (sums 2 col-partials) ----------------
__global__ void __launch_bounds__(1024) softmax_kernel(
    const float* __restrict__ epart, const int* __restrict__ key_len,
    float* __restrict__ attn) {
  __shared__ float sredM[16];
  __shared__ float sredS[16];
  const int b = blockIdx.x, tid = threadIdx.x;
  const int kl = key_len[b];
  float e0 = -3.0e38f, e1 = -3.0e38f;
  if (tid < kl)
    e0 = epart[(size_t)b*T_ + tid] + epart[((size_t)B_ + b)*T_ + tid];
  if (tid + 1024 < kl)
    e1 = epart[(size_t)b*T_ + tid+1024] + epart[((size_t)B_ + b)*T_ + tid+1024];
  float m = fmaxf(e0, e1);
  for (int s = 32; s; s >>= 1) m = fmaxf(m, __shfl_xor(m, s));
  if ((tid & 63) == 0) sredM[tid >> 6] = m;
  __syncthreads();
  float M = -3.0e38f;
  #pragma unroll
  for (int i = 0; i < 16; ++i) M = fmaxf(M, sredM[i]);
  const float p0 = (tid < kl) ? __expf(e0 - M) : 0.f;
  const float p1 = (tid + 1024 < kl) ? __expf(e1 - M) : 0.f;
  float s = p0 + p1;
  for (int k = 32; k; k >>= 1) s += __shfl_xor(s, k);
  if ((tid & 63) == 0) sredS[tid >> 6] = s;
  __syncthreads();
  float S = 0.f;
  #pragma unroll
  for (int i = 0; i < 16; ++i) S += sredS[i];
  const float inv = 1.f / S;
  attn[b*T_ + tid] = p0 * inv;
  attn[b*T_ + tid + 1024] = p1 * inv;
}

// ---------------- context: partial sums over t-chunks (float4), then combine ----------------
__global__ void __launch_bounds__(256) ctxpart_kernel(
    const float* __restrict__ value, const float* __restrict__ attn,
    const int* __restrict__ key_len, float* __restrict__ partial) {
  __shared__ float att_s[256];
  __shared__ float4 comb[128];
  const int b = blockIdx.y, ch = blockIdx.x;
  const int tid = threadIdx.x;
  const int c4 = tid & 127, half = tid >> 7;
  const int kl = key_len[b];
  const int tstart = ch * 256;
  const int tend = min(256, kl - tstart);
  float4 acc = make_float4(0.f, 0.f, 0.f, 0.f);
  if (tend > 0) {
    att_s[tid] = attn[b*T_ + tstart + tid];
    __syncthreads();
    const float4* vp = (const float4*)(value + ((size_t)b*T_ + tstart)*D_) + c4;
    for (int i = half; i < tend; i += 2) {
      const float w = att_s[i];
      const float4 v = vp[(size_t)i * 128];
      acc.x += w * v.x; acc.y += w * v.y; acc.z += w * v.z; acc.w += w * v.w;
    }
  }
  if (half == 1) comb[c4] = acc;
  __syncthreads();
  if (half == 0) {
    const float4 o = comb[c4];
    acc.x += o.x; acc.y += o.y; acc.z += o.z; acc.w += o.w;
    ((float4*)(partial + (size_t)(b*8 + ch)*D_))[c4] = acc;
  }
}

__global__ void __launch_bounds__(128) ctxsum_kernel(
    const float* __restrict__ partial, float* __restrict__ ctx) {
  const int b = blockIdx.x, tid = threadIdx.x;
  float4 s = make_float4(0.f, 0.f, 0.f, 0.f);
  #pragma unroll
  for (int c = 0; c < 8; ++c) {
    const float4 v = ((const float4*)(partial + (size_t)(b*8 + c)*D_))[tid];
    s.x += v.x; s.y += v.y; s.z += v.z; s.w += v.w;
  }
  ((float4*)(ctx + (size_t)b*D_))[tid] = s;
}

extern "C" void kernel_launch(void* const* d_in, const int* in_sizes, int n_in,
                              void* d_out, int out_size, void* d_ws, size_t ws_size,
                              hipStream_t stream) {
  const float* query  = (const float*)d_in[0];
  const float* keys   = (const float*)d_in[1];
  const float* value  = (const float*)d_in[2];
  const float* cover  = (const float*)d_in[3];
  const int*   key_len= (const int*)d_in[4];
  const float* Wq     = (const float*)d_in[5];
  const float* bq     = (const float*)d_in[6];
  const float* Wk     = (const float*)d_in[7];
  const float* Wc     = (const float*)d_in[8];
  const float* Wo     = (const float*)d_in[9];

  float* out = (float*)d_out;
  float* ctx_out  = out;            // [64,512]
  float* attn_out = out + B_*A_;    // [64,1,2048]

  float* ws = (float*)d_ws;
  float* qbuf    = ws;                                   // 32768 f32
  float* epart   = ws + 32768;                           // 2*131072 f32
  float* partial = ws + 32768 + 262144;                  // 262144 f32
  unsigned int* slab = (unsigned int*)(ws + 32768 + 262144 + 262144);  // 512 KB

  qproj_kernel<<<B_, 256, 0, stream>>>(query, Wq, bq, qbuf);
  wkprep_kernel<<<64, 256, 0, stream>>>(Wk, slab);
  energy_kernel<<<B_*(T_/BMT)*(A_/BNT), 512, 0, stream>>>(
      keys, cover, key_len, (const unsigned char*)slab, qbuf, Wc, Wo, epart);
  softmax_kernel<<<B_, 1024, 0, stream>>>(epart, key_len, attn_out);
  ctxpart_kernel<<<dim3(8, B_), 256, 0, stream>>>(value, attn_out, key_len, partial);
  ctxsum_kernel<<<B_, 128, 0, stream>>>(partial, ctx_out);
}

// Round 10
// 243.091 us; speedup vs baseline: 1.5821x; 1.1136x over previous
//
#include <hip/hip_runtime.h>
#include <hip/hip_bf16.h>

#define B_ 64
#define T_ 2048
#define D_ 512     // K dim of GEMM
#define A_ 512     // attention dim (N of GEMM)
#define BMT 128    // t-rows per block
#define BNT 256    // a-cols per block (N split in 2)
#define NIT 4      // K iterations, 2 K-tiles of 64 each

typedef float f32x4_t __attribute__((ext_vector_type(4)));
typedef short bf16x8_t __attribute__((ext_vector_type(8)));

#define GLL16(g, l) __builtin_amdgcn_global_load_lds( \
    (const __attribute__((address_space(1))) void*)(g), \
    (__attribute__((address_space(3))) void*)(l), 16, 0, 0)

#define SBAR __builtin_amdgcn_s_barrier()
#define LGKM0 do { asm volatile("s_waitcnt lgkmcnt(0)" ::: "memory"); \
                   __builtin_amdgcn_sched_barrier(0); } while (0)
#define VMW(N) asm volatile("s_waitcnt vmcnt(" #N ")" ::: "memory")

// ---------------- prep: q = query @ Wq + bq (fp32, exact) ----------------
__global__ void __launch_bounds__(256) qproj_kernel(
    const float* __restrict__ query, const float* __restrict__ Wq,
    const float* __restrict__ bq, float* __restrict__ qbuf) {
  __shared__ float qs[D_];
  const int b = blockIdx.x, tid = threadIdx.x;
  qs[tid] = query[b*D_ + tid];
  qs[tid+256] = query[b*D_ + tid + 256];
  __syncthreads();
  float a0 = bq[tid], a1 = bq[tid+256];
  for (int d = 0; d < D_; ++d) {
    const float qv = qs[d];
    a0 += qv * Wq[d*A_ + tid];
    a1 += qv * Wq[d*A_ + tid + 256];
  }
  qbuf[b*A_ + tid] = a0;
  qbuf[b*A_ + tid+256] = a1;
}

// ---- prep: Wk [D][A] fp32 -> slab [kt=8][ct=2][n=256][slot s = o ^ (n&7), 16B] ----
__global__ void __launch_bounds__(256) wkprep_kernel(
    const float* __restrict__ Wk, unsigned int* __restrict__ slab) {
  __shared__ float tile[64][65];
  const int kt = blockIdx.x >> 3;
  const int a0 = (blockIdx.x & 7) * 64;
  const int tid = threadIdx.x;
  #pragma unroll
  for (int p = 0; p < 16; ++p) {
    const int idx = p*256 + tid;
    const int k = idx >> 6, al = idx & 63;
    tile[k][al] = Wk[(kt*64 + k)*A_ + a0 + al];
  }
  __syncthreads();
  #pragma unroll
  for (int w = 0; w < 2; ++w) {
    const int idx = w*256 + tid;      // 0..511
    const int al = idx >> 3, c = idx & 7;
    const int a = a0 + al;
    const int n = a & 255;
    const int ctb = a >> 8;
    const int s = c ^ (n & 7);
    union { __hip_bfloat162 h[2]; uint2 u; } x, y;
    x.h[0] = __float22bfloat162_rn(make_float2(tile[c*8+0][al], tile[c*8+1][al]));
    x.h[1] = __float22bfloat162_rn(make_float2(tile[c*8+2][al], tile[c*8+3][al]));
    y.h[0] = __float22bfloat162_rn(make_float2(tile[c*8+4][al], tile[c*8+5][al]));
    y.h[1] = __float22bfloat162_rn(make_float2(tile[c*8+6][al], tile[c*8+7][al]));
    *(uint4*)(slab + ((kt*2 + ctb)*256 + n)*32 + s*4) =
        make_uint4(x.u.x, x.u.y, y.u.x, y.u.y);
  }
}

// ------- fused energy: 128x256 tile, 8-phase interleave, counted vmcnt -------
// LDS: A0 @0 (16K), A1 @16384, B0 @32768 (32K), B1 @65536, red @98304 (8K)
__global__ void __launch_bounds__(512, 2) energy_kernel(
    const float* __restrict__ keys, const float* __restrict__ cover,
    const int* __restrict__ key_len, const unsigned char* __restrict__ slabB,
    const float* __restrict__ qbuf, const float* __restrict__ Wc,
    const float* __restrict__ Wo, float* __restrict__ epart) {
  __shared__ __align__(16) unsigned char lds[106496];

  const int d = blockIdx.x;                 // 0..2047; XCD swizzle, ct-pairs co-XCD
  const int logical = (d & 7) * 256 + (d >> 3);
  const int ct = logical & 1;
  const int tt = (logical >> 1) & 15;
  const int b  = logical >> 5;
  const int t0 = tt * BMT;
  const int kl = key_len[b];
  if (t0 >= kl) return;

  const int tid = threadIdx.x;
  const int wid = tid >> 6, lane = tid & 63;
  const int lq = lane >> 4, lr = lane & 15;
  const int wm = wid >> 2, wn = wid & 3;    // wave tile: 64 rows x 64 cols
  const int sx = lr & 7;

  // fragment read bases (slot XOR depends only on lr&7; row steps of 16 keep it)
  const int aRow = (wm*64 + lr)*128;
  const int aOff0 = ((lq    ) ^ sx) << 4;   // kk=0
  const int aOff1 = ((4 + lq) ^ sx) << 4;   // kk=1
  const int bRow = 32768 + (wn*64 + lr)*128;

  // A staging role: thread covers row sr (0..127), k-quarter sq (16 floats)
  const int sr = tid >> 2, sq = tid & 3;
  const float* akey = keys + ((size_t)b*T_ + t0 + sr)*(size_t)D_ + sq*16;
  unsigned char* const awr = lds + sr*128;
  const int wofA = ((sq*2    ) ^ (sr & 7)) << 4;
  const int wofB = ((sq*2 + 1) ^ (sr & 7)) << 4;

  // B staging role: linear GLL copy of pre-swizzled slab tile
  const unsigned char* bsl = slabB + (size_t)ct*32768 + tid*16;
  unsigned char* const bwr = lds + 32768 + tid*16;

  f32x4_t acc[4][4];
  #pragma unroll
  for (int i = 0; i < 4; ++i)
    #pragma unroll
    for (int j = 0; j < 4; ++j) acc[i][j] = 0.0f;

  bf16x8_t aF[4], bF[2];
  f32x4_t pA[4], qA[4];

#define AGLOAD(kt, ARR) { const float* p_ = akey + (kt)*64; \
    ARR[0] = *(const f32x4_t*)(p_);      ARR[1] = *(const f32x4_t*)(p_ + 4); \
    ARR[2] = *(const f32x4_t*)(p_ + 8);  ARR[3] = *(const f32x4_t*)(p_ + 12); }

#define APACK(buf, ARR) { union { __hip_bfloat162 h[2]; uint2 u; } x_, y_; \
    x_.h[0] = __float22bfloat162_rn(make_float2(ARR[0][0], ARR[0][1])); \
    x_.h[1] = __float22bfloat162_rn(make_float2(ARR[0][2], ARR[0][3])); \
    y_.h[0] = __float22bfloat162_rn(make_float2(ARR[1][0], ARR[1][1])); \
    y_.h[1] = __float22bfloat162_rn(make_float2(ARR[1][2], ARR[1][3])); \
    *(uint4*)(awr + (buf)*16384 + wofA) = make_uint4(x_.u.x, x_.u.y, y_.u.x, y_.u.y); \
    x_.h[0] = __float22bfloat162_rn(make_float2(ARR[2][0], ARR[2][1])); \
    x_.h[1] = __float22bfloat162_rn(make_float2(ARR[2][2], ARR[2][3])); \
    y_.h[0] = __float22bfloat162_rn(make_float2(ARR[3][0], ARR[3][1])); \
    y_.h[1] = __float22bfloat162_rn(make_float2(ARR[3][2], ARR[3][3])); \
    *(uint4*)(awr + (buf)*16384 + wofB) = make_uint4(x_.u.x, x_.u.y, y_.u.x, y_.u.y); }

#define BGLL4(kt, buf) { const unsigned char* g_ = bsl + (size_t)(kt)*65536; \
    unsigned char* l_ = bwr + (buf)*32768; \
    GLL16(g_, l_); GLL16(g_ + 8192, l_ + 8192); \
    GLL16(g_ + 16384, l_ + 16384); GLL16(g_ + 24576, l_ + 24576); }

#define DSRA(buf, kk) { const unsigned char* p_ = lds + (buf)*16384 + aRow + ((kk) ? aOff1 : aOff0); \
    aF[0] = *(const bf16x8_t*)(p_);        aF[1] = *(const bf16x8_t*)(p_ + 2048); \
    aF[2] = *(const bf16x8_t*)(p_ + 4096); aF[3] = *(const bf16x8_t*)(p_ + 6144); }

#define DSRB(buf, kk, nh) { const unsigned char* p_ = lds + (buf)*32768 + bRow + ((kk) ? aOff1 : aOff0) + (nh)*4096; \
    bF[0] = *(const bf16x8_t*)(p_); bF[1] = *(const bf16x8_t*)(p_ + 2048); }

#define MFMA8(nh) { _Pragma("unroll") for (int mf_ = 0; mf_ < 4; ++mf_) { \
    _Pragma("unroll") for (int c_ = 0; c_ < 2; ++c_) \
      acc[mf_][(nh)*2 + c_] = __builtin_amdgcn_mfma_f32_16x16x32_bf16( \
          aF[mf_], bF[c_], acc[mf_][(nh)*2 + c_], 0, 0, 0); } }

#define PH_TAIL(nh) SBAR; LGKM0; __builtin_amdgcn_s_setprio(1); MFMA8(nh); \
    __builtin_amdgcn_s_setprio(0); SBAR

  // ---- prologue: stage K-tiles 0 (bufs 0) and 1 (bufs 1); one-time drain ----
  AGLOAD(0, pA); BGLL4(0, 0);
  AGLOAD(1, qA); BGLL4(1, 1);
  VMW(12); APACK(0, pA);
  VMW(4);  APACK(1, qA);
  VMW(0);
  LGKM0;
  SBAR;

  // ---- main loop: 4 iterations x 8 phases; c0=2it (buf0), c1=2it+1 (buf1) ----
  #pragma unroll
  for (int it = 0; it < NIT; ++it) {
    const int c1 = 2*it + 1, p0 = 2*it + 2, p1 = 2*it + 3;
    // ph1 (c0,kk0,nh0) + stage B(c1)
    DSRA(0, 0); DSRB(0, 0, 0);
    if (it >= 1) { BGLL4(c1, 1); }
    PH_TAIL(0);
    // ph2 (c0,kk0,nh1) + issue A-gloads(p0)
    DSRB(0, 0, 1);
    if (it <= 2) { AGLOAD(p0, pA); }
    PH_TAIL(1);
    // ph3 (c0,kk1,nh0) + pack A(c1)
    DSRA(0, 1); DSRB(0, 1, 0);
    if (it >= 1) {
      if (it <= 2) { VMW(8); } else { VMW(4); }
      APACK(1, qA);
    }
    PH_TAIL(0);
    // ph4 (c0,kk1,nh1) + B(c1) publication wait
    DSRB(0, 1, 1);
    if (it >= 1) { if (it <= 2) { VMW(4); } else { VMW(0); } }
    PH_TAIL(1);
    // ph5 (c1,kk0,nh0) + stage B(p0)
    DSRA(1, 0); DSRB(1, 0, 0);
    if (it <= 2) { BGLL4(p0, 0); }
    PH_TAIL(0);
    // ph6 (c1,kk0,nh1) + pack A(p0)
    DSRB(1, 0, 1);
    if (it <= 2) { VMW(4); APACK(0, pA); }
    PH_TAIL(1);
    // ph7 (c1,kk1,nh0)
    DSRA(1, 1); DSRB(1, 1, 0);
    PH_TAIL(0);
    // ph8 (c1,kk1,nh1) + issue A-gloads(p1) + B(p0) publication wait
    DSRB(1, 1, 1);
    if (it <= 2) { AGLOAD(p1, qA); VMW(4); }
    PH_TAIL(1);
  }

  // ---- epilogue: ep[t] = sum_n Wo[n] * tanh(acc + q[n] + cover[t]*Wc[n]) ----
  float* red = (float*)(lds + 98304);
  const float* qn  = qbuf + b*A_ + ct*BNT + wn*64 + lr;
  const float* wcn = Wc + ct*BNT + wn*64 + lr;
  const float* won = Wo + ct*BNT + wn*64 + lr;
  const float* covp = cover + (size_t)b*T_ + t0 + wm*64 + lq*4;
  float cov[4][4];
  #pragma unroll
  for (int mf = 0; mf < 4; ++mf)
    #pragma unroll
    for (int j = 0; j < 4; ++j) cov[mf][j] = covp[mf*16 + j];

  float ep[4][4];
  #pragma unroll
  for (int mf = 0; mf < 4; ++mf)
    #pragma unroll
    for (int j = 0; j < 4; ++j) ep[mf][j] = 0.f;

  #pragma unroll
  for (int nf = 0; nf < 4; ++nf) {
    const float qv = qn[nf*16];
    const float wc = wcn[nf*16];
    const float wo = won[nf*16];
    #pragma unroll
    for (int mf = 0; mf < 4; ++mf)
      #pragma unroll
      for (int j = 0; j < 4; ++j) {
        float p = acc[mf][nf][j] + qv + cov[mf][j] * wc;
        p = fminf(fmaxf(p, -15.f), 15.f);
        const float t2 = __expf(2.f * p);
        ep[mf][j] += wo * ((t2 - 1.f) * __builtin_amdgcn_rcpf(t2 + 1.f));
      }
  }
  #pragma unroll
  for (int mf = 0; mf < 4; ++mf)
    #pragma unroll
    for (int j = 0; j < 4; ++j) {
      float v = ep[mf][j];
      v += __shfl_xor(v, 1); v += __shfl_xor(v, 2);
      v += __shfl_xor(v, 4); v += __shfl_xor(v, 8);
      ep[mf][j] = v;
    }
  if (lr == 0) {
    #pragma unroll
    for (int mf = 0; mf < 4; ++mf)
      #pragma unroll
      for (int j = 0; j < 4; ++j)
        red[wid*64 + mf*16 + lq*4 + j] = ep[mf][j];
  }
  __syncthreads();
  if (tid < BMT) {
    const int r = tid, wmr = r >> 6, ro = r & 63;
    epart[((size_t)ct*B_ + b)*T_ + t0 + r] =
        red[(wmr*4+0)*64 + ro] + red[(wmr*4+1)*64 + ro] +
        red[(wmr*4+2)*64 + ro] + red[(wmr*4+3)*64 + ro];
  }
}

// ---------------- masked softmax over T (sums 2 col-partials) ----------------
__global__ void __launch_bounds__(1024) softmax_kernel(
    const float* __restrict__ epart, const int* __restrict__ key_len,
    float* __restrict__ attn) {
  __shared__ float sredM[16];
  __shared__ float sredS[16];
  const int b = blockIdx.x, tid = threadIdx.x;
  const int kl = key_len[b];
  float e0 = -3.0e38f, e1 = -3.0e38f;
  if (tid < kl)
    e0 = epart[(size_t)b*T_ + tid] + epart[((size_t)B_ + b)*T_ + tid];
  if (tid + 1024 < kl)
    e1 = epart[(size_t)b*T_ + tid+1024] + epart[((size_t)B_ + b)*T_ + tid+1024];
  float m = fmaxf(e0, e1);
  for (int s = 32; s; s >>= 1) m = fmaxf(m, __shfl_xor(m, s));
  if ((tid & 63) == 0) sredM[tid >> 6] = m;
  __syncthreads();
  float M = -3.0e38f;
  #pragma unroll
  for (int i = 0; i < 16; ++i) M = fmaxf(M, sredM[i]);
  const float p0 = (tid < kl) ? __expf(e0 - M) : 0.f;
  const float p1 = (tid + 1024 < kl) ? __expf(e1 - M) : 0.f;
  float s = p0 + p1;
  for (int k = 32; k; k >>= 1) s += __shfl_xor(s, k);
  if ((tid & 63) == 0) sredS[tid >> 6] = s;
  __syncthreads();
  float S = 0.f;
  #pragma unroll
  for (int i = 0; i < 16; ++i) S += sredS[i];
  const float inv = 1.f / S;
  attn[b*T_ + tid] = p0 * inv;
  attn[b*T_ + tid + 1024] = p1 * inv;
}

// ---------------- context: partial sums over t-chunks (float4), then combine ----------------
__global__ void __launch_bounds__(256) ctxpart_kernel(
    const float* __restrict__ value, const float* __restrict__ attn,
    const int* __restrict__ key_len, float* __restrict__ partial) {
  __shared__ float att_s[256];
  __shared__ float4 comb[128];
  const int b = blockIdx.y, ch = blockIdx.x;
  const int tid = threadIdx.x;
  const int c4 = tid & 127, half = tid >> 7;
  const int kl = key_len[b];
  const int tstart = ch * 256;
  const int tend = min(256, kl - tstart);
  float4 acc = make_float4(0.f, 0.f, 0.f, 0.f);
  if (tend > 0) {
    att_s[tid] = attn[b*T_ + tstart + tid];
    __syncthreads();
    const float4* vp = (const float4*)(value + ((size_t)b*T_ + tstart)*D_) + c4;
    for (int i = half; i < tend; i += 2) {
      const float w = att_s[i];
      const float4 v = vp[(size_t)i * 128];
      acc.x += w * v.x; acc.y += w * v.y; acc.z += w * v.z; acc.w += w * v.w;
    }
  }
  if (half == 1) comb[c4] = acc;
  __syncthreads();
  if (half == 0) {
    const float4 o = comb[c4];
    acc.x += o.x; acc.y += o.y; acc.z += o.z; acc.w += o.w;
    ((float4*)(partial + (size_t)(b*8 + ch)*D_))[c4] = acc;
  }
}

__global__ void __launch_bounds__(128) ctxsum_kernel(
    const float* __restrict__ partial, float* __restrict__ ctx) {
  const int b = blockIdx.x, tid = threadIdx.x;
  float4 s = make_float4(0.f, 0.f, 0.f, 0.f);
  #pragma unroll
  for (int c = 0; c < 8; ++c) {
    const float4 v = ((const float4*)(partial + (size_t)(b*8 + c)*D_))[tid];
    s.x += v.x; s.y += v.y; s.z += v.z; s.w += v.w;
  }
  ((float4*)(ctx + (size_t)b*D_))[tid] = s;
}

extern "C" void kernel_launch(void* const* d_in, const int* in_sizes, int n_in,
                              void* d_out, int out_size, void* d_ws, size_t ws_size,
                              hipStream_t stream) {
  const float* query  = (const float*)d_in[0];
  const float* keys   = (const float*)d_in[1];
  const float* value  = (const float*)d_in[2];
  const float* cover  = (const float*)d_in[3];
  const int*   key_len= (const int*)d_in[4];
  const float* Wq     = (const float*)d_in[5];
  const float* bq     = (const float*)d_in[6];
  const float* Wk     = (const float*)d_in[7];
  const float* Wc     = (const float*)d_in[8];
  const float* Wo     = (const float*)d_in[9];

  float* out = (float*)d_out;
  float* ctx_out  = out;            // [64,512]
  float* attn_out = out + B_*A_;    // [64,1,2048]

  float* ws = (float*)d_ws;
  float* qbuf    = ws;                                   // 32768 f32
  float* epart   = ws + 32768;                           // 2*131072 f32
  float* partial = ws + 32768 + 262144;                  // 262144 f32
  unsigned int* slab = (unsigned int*)(ws + 32768 + 262144 + 262144);  // 512 KB

  qproj_kernel<<<B_, 256, 0, stream>>>(query, Wq, bq, qbuf);
  wkprep_kernel<<<64, 256, 0, stream>>>(Wk, slab);
  energy_kernel<<<B_*(T_/BMT)*(A_/BNT), 512, 0, stream>>>(
      keys, cover, key_len, (const unsigned char*)slab, qbuf, Wc, Wo, epart);
  softmax_kernel<<<B_, 1024, 0, stream>>>(epart, key_len, attn_out);
  ctxpart_kernel<<<dim3(8, B_), 256, 0, stream>>>(value, attn_out, key_len, partial);
  ctxsum_kernel<<<B_, 128, 0, stream>>>(partial, ctx_out);
}